// Round 1
// baseline (629.731 us; speedup 1.0000x reference)
//
#include <hip/hip_runtime.h>
#include <math.h>

#define NPTS 128   // N (points per ray) == blockDim
#define NWAVE (NPTS / 64)

// One block per batch row b; thread n handles point (b, n).
// Weights are read with wave-uniform indices -> scalar loads (SGPR) + v_fmac.
__global__ __launch_bounds__(NPTS) void surf_fused(
    const int*   __restrict__ x,     // (B, N, 6) int32
    const float* __restrict__ dvec,  // (B, 16)
    const float* __restrict__ gw,    // (TABLE, 4)
    const float* __restrict__ W0,    // (34, 64) row-major
    const float* __restrict__ b0,    // (64)
    const float* __restrict__ W1,    // (64, 64)
    const float* __restrict__ b1,    // (64)
    const float* __restrict__ W2,    // (64, 3)
    const float* __restrict__ b2,    // (3)
    float* __restrict__ out_sigma,   // (B, N)
    float* __restrict__ out_color)   // (B, 3)
{
    const int b = blockIdx.x;
    const int n = threadIdx.x;

    __shared__ float s_dirW[64];          // b0 + d[b] @ W0[0:16,:]
    __shared__ float s_sigma[NPTS];
    __shared__ float s_wmax[NWAVE];
    __shared__ float s_csum[NWAVE][3];

    // ---- per-block direction contribution (shared by all 128 points) ----
    if (n < 64) {
        float acc = b0[n];
        const float* db = dvec + (size_t)b * 16;
        #pragma unroll
        for (int i = 0; i < 16; ++i)
            acc = fmaf(db[i], W0[i * 64 + n], acc);
        s_dirW[n] = acc;
    }

    // ---- gather 6 levels, density product, geo features ----
    const int* xp = x + ((size_t)b * NPTS + n) * 6;
    float geo[18];
    float sig = 1.0f;
    #pragma unroll
    for (int l = 0; l < 6; ++l) {
        const int idx = xp[l];
        const float4 v = *(const float4*)(gw + (size_t)idx * 4);
        sig *= fminf(fmaxf(v.x, 0.0f), 1.0f);
        geo[l * 3 + 0] = v.y;
        geo[l * 3 + 1] = v.z;
        geo[l * 3 + 2] = v.w;
    }
    const float sigma0 = sig + 1e-4f;

    // ---- max over the 128 points of this row ----
    float m = sigma0;
    #pragma unroll
    for (int off = 32; off > 0; off >>= 1)
        m = fmaxf(m, __shfl_xor(m, off));
    if ((n & 63) == 0) s_wmax[n >> 6] = m;
    __syncthreads();                       // covers s_dirW + s_wmax writes
    float maxv = s_wmax[0];
    #pragma unroll
    for (int w = 1; w < NWAVE; ++w) maxv = fmaxf(maxv, s_wmax[w]);

    const float sigma = sigma0 / maxv;
    s_sigma[n] = sigma;
    out_sigma[(size_t)b * NPTS + n] = sigma;
    __syncthreads();
    // transparentBefore: 1 for n==0, else (1 - sigma[n-1])
    const float cw = (n == 0) ? sigma : (1.0f - s_sigma[n - 1]) * sigma;

    // ---- layer 0: geo (18 dims) only; dir part precomputed ----
    float h1[64];
    #pragma unroll
    for (int jt = 0; jt < 4; ++jt) {
        float acc[16];
        #pragma unroll
        for (int k = 0; k < 16; ++k) acc[k] = s_dirW[jt * 16 + k];
        #pragma unroll
        for (int g = 0; g < 18; ++g) {
            const float hg = geo[g];
            #pragma unroll
            for (int k = 0; k < 16; ++k)
                acc[k] = fmaf(hg, W0[(16 + g) * 64 + jt * 16 + k], acc[k]);
        }
        #pragma unroll
        for (int k = 0; k < 16; ++k) h1[jt * 16 + k] = fmaxf(acc[k], 0.0f);
    }

    // ---- layer 1 (64x64) fused with layer 2 (64x3) ----
    float c0 = b2[0], c1 = b2[1], c2 = b2[2];
    #pragma unroll
    for (int jt = 0; jt < 4; ++jt) {
        float acc[16];
        #pragma unroll
        for (int k = 0; k < 16; ++k) acc[k] = b1[jt * 16 + k];
        #pragma unroll
        for (int i = 0; i < 64; ++i) {
            const float hv = h1[i];
            #pragma unroll
            for (int k = 0; k < 16; ++k)
                acc[k] = fmaf(hv, W1[i * 64 + jt * 16 + k], acc[k]);
        }
        #pragma unroll
        for (int k = 0; k < 16; ++k) {
            const float hv = fmaxf(acc[k], 0.0f);
            const int j = jt * 16 + k;
            c0 = fmaf(hv, W2[j * 3 + 0], c0);
            c1 = fmaf(hv, W2[j * 3 + 1], c1);
            c2 = fmaf(hv, W2[j * 3 + 2], c2);
        }
    }

    const float col0 = 1.0f / (1.0f + __expf(-c0));
    const float col1 = 1.0f / (1.0f + __expf(-c1));
    const float col2 = 1.0f / (1.0f + __expf(-c2));

    // ---- weighted color sum over the 128 points ----
    float r0 = cw * col0, r1 = cw * col1, r2 = cw * col2;
    #pragma unroll
    for (int off = 32; off > 0; off >>= 1) {
        r0 += __shfl_xor(r0, off);
        r1 += __shfl_xor(r1, off);
        r2 += __shfl_xor(r2, off);
    }
    if ((n & 63) == 0) {
        s_csum[n >> 6][0] = r0;
        s_csum[n >> 6][1] = r1;
        s_csum[n >> 6][2] = r2;
    }
    __syncthreads();
    if (n == 0) {
        float o0 = s_csum[0][0], o1 = s_csum[0][1], o2 = s_csum[0][2];
        #pragma unroll
        for (int w = 1; w < NWAVE; ++w) {
            o0 += s_csum[w][0];
            o1 += s_csum[w][1];
            o2 += s_csum[w][2];
        }
        out_color[(size_t)b * 3 + 0] = o0;
        out_color[(size_t)b * 3 + 1] = o1;
        out_color[(size_t)b * 3 + 2] = o2;
    }
}

extern "C" void kernel_launch(void* const* d_in, const int* in_sizes, int n_in,
                              void* d_out, int out_size, void* d_ws, size_t ws_size,
                              hipStream_t stream) {
    const int*   x    = (const int*)d_in[0];
    const float* dvec = (const float*)d_in[1];
    const float* gw   = (const float*)d_in[2];
    const float* W0   = (const float*)d_in[3];
    const float* b0   = (const float*)d_in[4];
    const float* W1   = (const float*)d_in[5];
    const float* b1   = (const float*)d_in[6];
    const float* W2   = (const float*)d_in[7];
    const float* b2   = (const float*)d_in[8];

    const int B = in_sizes[1] / 16;          // d is (B, 16)
    float* out_sigma = (float*)d_out;                    // (B, N)
    float* out_color = (float*)d_out + (size_t)B * NPTS; // (B, 3)

    surf_fused<<<B, NPTS, 0, stream>>>(x, dvec, gw, W0, b0, W1, b1, W2, b2,
                                       out_sigma, out_color);
}

// Round 2
// 336.389 us; speedup vs baseline: 1.8720x; 1.8720x over previous
//
#include <hip/hip_runtime.h>
#include <math.h>

// ---------------------------------------------------------------------------
// SurfNetwork: hash-grid gather -> sigma product/normalize -> MLP 34->64->64->3
// MLP runs on bf16 MFMA (16x16x32). One ray (128 points) per 512-thread block,
// 8 waves, each wave = one M=16 row tile. Weights pre-packed to B-fragment
// order in d_ws by a setup kernel (same work every call; ws is re-poisoned).
// Fragment layouts (guide-verified on gfx950):
//   A: lane holds A[m=lane&15][k=(lane>>4)*8+j], j=0..7
//   B: lane holds B[k=(lane>>4)*8+j][n=lane&15]
//   C: lane reg r holds C[row=(lane>>4)*4+r][col=lane&15]
// ---------------------------------------------------------------------------

typedef short bf16x8 __attribute__((ext_vector_type(8)));
typedef float floatx4 __attribute__((ext_vector_type(4)));

__device__ inline unsigned short f2b(float f) {  // fp32 -> bf16 RNE
    union { float f; unsigned u; } v; v.f = f;
    unsigned r = v.u + 0x7FFF + ((v.u >> 16) & 1);
    return (unsigned short)(r >> 16);
}

// ws layout (bf16/ushort units):
//   [0    .. 2047]  W0geo frags: f = ntile(0..3);          k=geo idx (0..17, pad 32)
//   [2048 .. 6143]  W1    frags: f = kstep*4 + ntile;      k 0..63
//   [6144 .. 7167]  W2    frags: f = kstep(0..1), N=16 pad; n<3 valid
__global__ void build_frags(const float* __restrict__ W0,
                            const float* __restrict__ W1,
                            const float* __restrict__ W2,
                            unsigned short* __restrict__ wsf) {
    int tid = blockIdx.x * blockDim.x + threadIdx.x;
    if (tid >= 7168) return;
    int lane, j, k, n;
    float val;
    if (tid < 2048) {
        int f = tid >> 9, r = tid & 511; lane = r >> 3; j = r & 7;
        k = ((lane >> 4) * 8) + j;            // geo feature index
        n = f * 16 + (lane & 15);
        val = (k < 18) ? W0[(16 + k) * 64 + n] : 0.0f;
    } else if (tid < 6144) {
        int e = tid - 2048;
        int f = e >> 9, r = e & 511; lane = r >> 3; j = r & 7;
        int ks = f >> 2, nt = f & 3;
        k = ks * 32 + ((lane >> 4) * 8) + j;
        n = nt * 16 + (lane & 15);
        val = W1[k * 64 + n];
    } else {
        int e = tid - 6144;
        int f = e >> 9, r = e & 511; lane = r >> 3; j = r & 7;
        k = f * 32 + ((lane >> 4) * 8) + j;
        n = lane & 15;
        val = (n < 3) ? W2[k * 3 + n] : 0.0f;
    }
    wsf[tid] = f2b(val);
}

__global__ __launch_bounds__(512, 4) void surf_main(
    const int*   __restrict__ x,     // (B, 128, 6)
    const float* __restrict__ dvec,  // (B, 16)
    const float* __restrict__ gw,    // (TABLE, 4)
    const float* __restrict__ W0,    // (34, 64)  (dir rows used here)
    const float* __restrict__ b0,    // (64)
    const float* __restrict__ b1,    // (64)
    const float* __restrict__ b2,    // (3)
    const unsigned short* __restrict__ wsf,
    float* __restrict__ out_sigma,   // (B, 128)
    float* __restrict__ out_color)   // (B, 3)
{
    const int b    = blockIdx.x;
    const int t    = threadIdx.x;
    const int lane = t & 63;
    const int w    = t >> 6;         // wave id 0..7 -> rows w*16..w*16+15
    const int l15  = lane & 15;
    const int quad = lane >> 4;

    __shared__ unsigned short A0[128 * 40];  // geo bf16, K padded to 32, stride 40
    __shared__ unsigned short H1[128 * 72];  // hidden bf16, stride 72 (reused for h2)
    __shared__ float s_sigl[768];            // clipped level densities, x memory order
    __shared__ float s_dirW[64];             // b0 + d[b] @ W0[0:16,:]
    __shared__ float s_wmax[2];
    __shared__ float s_cw[128];              // compositing weights
    __shared__ float s_part[8 * 16];

    // ---- weight B-fragments (coalesced, L1/L2-resident; issue early) ----
    bf16x8 bw0[4], bw1[8];
    #pragma unroll
    for (int i = 0; i < 4; ++i) bw0[i] = *(const bf16x8*)(wsf + i * 512 + lane * 8);
    #pragma unroll
    for (int i = 0; i < 8; ++i) bw1[i] = *(const bf16x8*)(wsf + 2048 + i * 512 + lane * 8);

    // ---- stage: coalesced x read, random gather, LDS writes ----
    #pragma unroll
    for (int e0 = 0; e0 < 768; e0 += 512) {
        int e = e0 + t;
        if (e < 768) {
            int xv = x[(size_t)b * 768 + e];
            int point = e / 6;
            int level = e - point * 6;
            float4 v = *(const float4*)(gw + (size_t)xv * 4);
            s_sigl[e] = fminf(fmaxf(v.x, 0.0f), 1.0f);
            unsigned short* a = A0 + point * 40 + level * 3;
            a[0] = f2b(v.y); a[1] = f2b(v.z); a[2] = f2b(v.w);
        }
    }
    if (t < 128) {  // zero-pad geo cols 18..31
        unsigned short* a = A0 + t * 40;
        *(unsigned int*)(a + 18) = 0u;
        *(uint2*)(a + 20) = make_uint2(0u, 0u);
        *(uint2*)(a + 24) = make_uint2(0u, 0u);
        *(uint2*)(a + 28) = make_uint2(0u, 0u);
    }
    if (t < 64) {   // per-ray direction contribution (fp32)
        float acc = b0[t];
        const float* db = dvec + (size_t)b * 16;
        #pragma unroll
        for (int i = 0; i < 16; ++i) acc = fmaf(db[i], W0[i * 64 + t], acc);
        s_dirW[t] = acc;
    }
    __syncthreads();

    // ---- sigma: product of 6 clipped densities, max over ray, normalize ----
    float sigma0 = 0.0f;
    if (t < 128) {
        float p = 1.0f;
        #pragma unroll
        for (int l = 0; l < 6; ++l) p *= s_sigl[t * 6 + l];
        sigma0 = p + 1e-4f;
        float m = sigma0;
        #pragma unroll
        for (int off = 32; off; off >>= 1) m = fmaxf(m, __shfl_xor(m, off));
        if (lane == 0) s_wmax[w] = m;
    }
    __syncthreads();
    if (t < 128) {
        float maxv  = fmaxf(s_wmax[0], s_wmax[1]);
        float sigma = sigma0 / maxv;
        out_sigma[(size_t)b * 128 + t] = sigma;
        float cw;
        if (t == 0) cw = sigma;
        else {
            float pp = 1.0f;
            #pragma unroll
            for (int l = 0; l < 6; ++l) pp *= s_sigl[(t - 1) * 6 + l];
            float sprev = (pp + 1e-4f) / maxv;
            cw = (1.0f - sprev) * sigma;
        }
        s_cw[t] = cw;
    }

    // ---- layer 0 (geo part via MFMA, dir part as fp32 C-init) ----
    const int row = w * 16 + l15;
    bf16x8 a0 = *(const bf16x8*)(A0 + row * 40 + quad * 8);
    floatx4 acc0[4];
    #pragma unroll
    for (int nt = 0; nt < 4; ++nt) {
        float dw = s_dirW[nt * 16 + l15];
        acc0[nt] = (floatx4){dw, dw, dw, dw};
        acc0[nt] = __builtin_amdgcn_mfma_f32_16x16x32_bf16(a0, bw0[nt], acc0[nt], 0, 0, 0);
    }
    // relu -> bf16 -> LDS in A-layout (wave-private rows; in-wave LDS order is safe)
    #pragma unroll
    for (int nt = 0; nt < 4; ++nt)
        #pragma unroll
        for (int r = 0; r < 4; ++r) {
            int pr = w * 16 + quad * 4 + r;
            H1[pr * 72 + nt * 16 + l15] = f2b(fmaxf(acc0[nt][r], 0.0f));
        }

    // ---- layer 1 (64x64) ----
    bf16x8 a1a = *(const bf16x8*)(H1 + row * 72 + quad * 8);
    bf16x8 a1b = *(const bf16x8*)(H1 + row * 72 + 32 + quad * 8);
    floatx4 acc1[4];
    #pragma unroll
    for (int nt = 0; nt < 4; ++nt) {
        float bb = b1[nt * 16 + l15];
        acc1[nt] = (floatx4){bb, bb, bb, bb};
        acc1[nt] = __builtin_amdgcn_mfma_f32_16x16x32_bf16(a1a, bw1[nt],     acc1[nt], 0, 0, 0);
        acc1[nt] = __builtin_amdgcn_mfma_f32_16x16x32_bf16(a1b, bw1[4 + nt], acc1[nt], 0, 0, 0);
    }
    // relu -> bf16 -> LDS (overwrite own rows)
    #pragma unroll
    for (int nt = 0; nt < 4; ++nt)
        #pragma unroll
        for (int r = 0; r < 4; ++r) {
            int pr = w * 16 + quad * 4 + r;
            H1[pr * 72 + nt * 16 + l15] = f2b(fmaxf(acc1[nt][r], 0.0f));
        }

    // ---- layer 2 (64->3, N padded to 16) ----
    bf16x8 bw2a = *(const bf16x8*)(wsf + 6144 + lane * 8);
    bf16x8 bw2b = *(const bf16x8*)(wsf + 6144 + 512 + lane * 8);
    bf16x8 a2a = *(const bf16x8*)(H1 + row * 72 + quad * 8);
    bf16x8 a2b = *(const bf16x8*)(H1 + row * 72 + 32 + quad * 8);
    float bias2 = (l15 < 3) ? b2[l15] : 0.0f;
    floatx4 acc2 = (floatx4){bias2, bias2, bias2, bias2};
    acc2 = __builtin_amdgcn_mfma_f32_16x16x32_bf16(a2a, bw2a, acc2, 0, 0, 0);
    acc2 = __builtin_amdgcn_mfma_f32_16x16x32_bf16(a2b, bw2b, acc2, 0, 0, 0);

    __syncthreads();  // s_cw ready
    // sigmoid + compositing weight + reduce over the wave's 16 points
    float sum = 0.0f;
    #pragma unroll
    for (int r = 0; r < 4; ++r) {
        float col = 1.0f / (1.0f + __expf(-acc2[r]));
        float cw  = s_cw[w * 16 + quad * 4 + r];
        sum += cw * col;
    }
    sum += __shfl_xor(sum, 16);
    sum += __shfl_xor(sum, 32);
    if (lane < 16) s_part[w * 16 + lane] = sum;   // col = lane
    __syncthreads();
    if (t < 3) {
        float o = 0.0f;
        #pragma unroll
        for (int ww = 0; ww < 8; ++ww) o += s_part[ww * 16 + t];
        out_color[(size_t)b * 3 + t] = o;
    }
}

extern "C" void kernel_launch(void* const* d_in, const int* in_sizes, int n_in,
                              void* d_out, int out_size, void* d_ws, size_t ws_size,
                              hipStream_t stream) {
    const int*   x    = (const int*)d_in[0];
    const float* dvec = (const float*)d_in[1];
    const float* gw   = (const float*)d_in[2];
    const float* W0   = (const float*)d_in[3];
    const float* b0   = (const float*)d_in[4];
    const float* W1   = (const float*)d_in[5];
    const float* b1   = (const float*)d_in[6];
    const float* W2   = (const float*)d_in[7];
    const float* b2   = (const float*)d_in[8];

    const int B = in_sizes[1] / 16;                       // d is (B, 16)
    float* out_sigma = (float*)d_out;                     // (B, 128)
    float* out_color = (float*)d_out + (size_t)B * 128;   // (B, 3)
    unsigned short* wsf = (unsigned short*)d_ws;          // 14336 B used

    build_frags<<<14, 512, 0, stream>>>(W0, W1, W2, wsf);
    surf_main<<<B, 512, 0, stream>>>(x, dvec, gw, W0, b0, b1, b2, wsf,
                                     out_sigma, out_color);
}